// Round 4
// baseline (79.281 us; speedup 1.0000x reference)
//
#include <hip/hip_runtime.h>

// GaussianHistogram: hist[b,i,j] = sum_n exp(-pi*(u1-i)^2) * exp(-pi*(u2-j)^2) * mask
// u = (x - MIN_V)/DELTA - 0.5 ; COEF == 1.0 exactly.
//
// v5: PHASE-SHIFTED 16-bit packed LDS atomics -> 3 ds_add_u64 lane-ops/point.
// Measured DS-atomic cost model (v1: 9xf32=10.4cyc/op; v4: 6xu64=14.3cyc/op):
// ~6.5 cyc fixed per lane-op + ~3.9 cyc per 4B bank RMW. Kernel time == DS time
// (VALU ~7us hidden). So minimize lane-ops at fixed footprint:
//  - 16-bit fixed-point fields: one u64 = 4 adjacent columns.
//  - A 3-tap col window [j0-1, j0+1] fits ONE 4-col word in exactly one of two
//    phase-shifted packings: even-aligned window start e = (j0-1)&~1;
//    phase = (e>>1)&1 selects tile copy (phase0: cols 4w.., phase1: cols 4w+2..),
//    word = e>>2 in BOTH phases. 4th field = bonus tap (dist<=2.5, exact weight,
//    improves accuracy; reference sums ALL cols so extra taps only help).
//  - 3 exact row taps x 1 word = 3 lane-ops/point (v4: 6, v1: 9).
// Predicted kernel ~20.5us (3*14.3cyc*1024pts/CU), total ~63us w/ harness fill.
//
// Overflow: per-cell mass (COEF=1) is ~0.25 avg, < ~30 worst-case Poisson tail,
// and is SPLIT across the two phases; field sum < 31K << 65535 -> no cross-field
// carry in the u64 adds. Rounding noise ~1.5e-3 vs 8.6e-2 threshold (v1/v4
// measured 0.0156, dominated by harness fp32 noise).
//
// Ownership: block = (batch, 8-row tile); scans all 32768 pts of its batch
// (inputs L2-resident), deposits owned-row taps into tile[2][8][64] u64 (8 KB),
// unpacks E+O phases and stores. No global atomics, no ws, no memset.

#define BINS   256
#define NPTS   32768
#define BATCH  8
#define TROWS  8                  // rows per tile
#define NTILE  (BINS / TROWS)     // 32 tiles -> 256 blocks, 1/CU
#define WORDS  64                 // u64 words per row per phase

static constexpr float kInvDelta = 256.0f / 1.5f;                  // 1/DELTA
static constexpr float kUAdd     = 0.25f * (256.0f / 1.5f) - 0.5f; // (x-MIN)/D - 0.5
static constexpr float kPi       = 3.14159265358979323846f;
static constexpr float kFix      = 1024.0f;                        // 16-bit fixed .10
static constexpr float kInvFix   = 1.0f / 1024.0f;

__global__ __launch_bounds__(1024) void gh_gather(
    const float* __restrict__ x1, const float* __restrict__ x2,
    const float* __restrict__ mask, float* __restrict__ out)
{
    __shared__ unsigned long long tile[2 * TROWS * WORDS];   // 1024 u64 = 8 KB
    const int tid = threadIdx.x;
    const int r0  = blockIdx.x * TROWS;    // first output row owned
    const int b   = blockIdx.y;

    tile[tid] = 0ULL;                      // 1024 threads == 1024 words
    __syncthreads();

    const float4* X1 = (const float4*)(x1   + b * NPTS);
    const float4* X2 = (const float4*)(x2   + b * NPTS);
    const float4* M  = (const float4*)(mask + b * NPTS);

#pragma unroll 2
    for (int it = 0; it < NPTS / 4096; ++it) {   // 8 iterations, 4 points each
        const int n4 = it * 1024 + tid;
        const float4 a4 = X1[n4];
        const float4 b4 = X2[n4];
        const float4 m4 = M[n4];

        const float pv1[4] = {a4.x, a4.y, a4.z, a4.w};
        const float pv2[4] = {b4.x, b4.y, b4.z, b4.w};
        const float pm[4]  = {m4.x, m4.y, m4.z, m4.w};

#pragma unroll
        for (int k = 0; k < 4; ++k) {
            const float u1 = fmaf(pv1[k], kInvDelta, kUAdd);
            const float u2 = fmaf(pv2[k], kInvDelta, kUAdd);
            const float fi = rintf(u1);
            const int   i0 = (int)fi;
            const float t1 = u1 - fi;             // in [-0.5, 0.5]

            // even window start containing cols [j0-1, j0+1] in 4 cols
            int e = (((int)rintf(u2)) - 1) & ~1;
            e = min(250, max(0, e));              // memory-safety (no-op in-spec)
            const int  ph   = (e >> 1) & 1;       // phase: which tile copy
            const int  word = e >> 2;             // same formula both phases
            const float t2  = u2 - (float)e;      // offset of u2 from col e

            // 3 exact row weights
            float w1a[3];
#pragma unroll
            for (int a = 0; a < 3; ++a) {
                const float d = t1 - (float)(a - 1);
                w1a[a] = __expf(-kPi * d * d);
            }
            // 4 exact col-field weights (mask + fixed scale folded in)
            float W2[4];
#pragma unroll
            for (int c = 0; c < 4; ++c) {
                const float d = t2 - (float)c;
                W2[c] = __expf(-kPi * d * d) * (pm[k] * kFix);
            }

            const int rbase = i0 - 1 - r0;        // tile-relative row of tap a=0
            const int pbase = ph * (TROWS * WORDS) + word;
#pragma unroll
            for (int a = 0; a < 3; ++a) {
                const int r = rbase + a;
                if ((unsigned)r < TROWS) {        // row owned by this block?
                    const float wa = w1a[a];
                    const unsigned f0 = (unsigned)fmaf(wa, W2[0], 0.5f);
                    const unsigned f1 = (unsigned)fmaf(wa, W2[1], 0.5f);
                    const unsigned f2 = (unsigned)fmaf(wa, W2[2], 0.5f);
                    const unsigned f3 = (unsigned)fmaf(wa, W2[3], 0.5f);
                    const unsigned long long w =
                        (unsigned long long)(f0 | (f1 << 16)) |
                        ((unsigned long long)(f2 | (f3 << 16)) << 32);
                    atomicAdd(&tile[pbase + r * WORDS], w);   // ds_add_u64
                }
            }
        }
    }
    __syncthreads();

    // unpack both phases, sum, store owned 8x256 tile (coalesced float2/thread)
    {
        const int cell0 = tid * 2;            // 2048 cells / 1024 threads
        const int r  = cell0 >> 8;            // 0..7
        const int c0 = cell0 & 255;
        float2 f2v;
        float* fp = &f2v.x;
#pragma unroll
        for (int i = 0; i < 2; ++i) {
            const int c = c0 + i;
            const unsigned long long we = tile[r * WORDS + (c >> 2)];
            unsigned v = (unsigned)(we >> (16 * (c & 3))) & 0xFFFFu;
            if (c >= 2) {
                const unsigned long long wo =
                    tile[TROWS * WORDS + r * WORDS + ((c - 2) >> 2)];
                v += (unsigned)(wo >> (16 * ((c - 2) & 3))) & 0xFFFFu;
            }
            fp[i] = (float)v * kInvFix;
        }
        float2* o2 = (float2*)(out + ((size_t)b * BINS + r0 + r) * BINS + c0);
        *o2 = f2v;
    }
}

extern "C" void kernel_launch(void* const* d_in, const int* in_sizes, int n_in,
                              void* d_out, int out_size, void* d_ws, size_t ws_size,
                              hipStream_t stream) {
    const float* x1   = (const float*)d_in[0];
    const float* x2   = (const float*)d_in[1];
    const float* mask = (const float*)d_in[2];
    float*       out  = (float*)d_out;

    gh_gather<<<dim3(NTILE, BATCH), 1024, 0, stream>>>(x1, x2, mask, out);
}

// Round 5
// 75.384 us; speedup vs baseline: 1.0517x; 1.0517x over previous
//
#include <hip/hip_runtime.h>

// GaussianHistogram: hist[b,i,j] = sum_n exp(-pi*(u1-i)^2) * exp(-pi*(u2-j)^2) * mask
// u = (x - MIN_V)/DELTA - 0.5 ; COEF == 1.0 exactly.
//
// v6: multi-theory discriminator. v1..v5 all land at 37-42us regardless of
// evals/CU (32768 vs 8192) and DS lane-ops/CU (9216 vs 3072) -> no single-pipe
// model fits; floor is shared structure. v6 reduces EVERY candidate at once:
//  - point-chunking (4 chunks): per-CU evals 32768 -> 16384 (VALU/2)
//  - v5 phase-shifted 16-bit packing kept: 3 ds_add_u64 lane-ops/point (min DS)
//  - 512-thread blocks: VGPR cap 128 -> 256 (kills any spill), finer dispatch
//    granule (512 blocks, 2/CU) halving imbalance quantum.
// Partial tiles -> ws, tiny unpack-reduce kernel merges (L2-resident, ~3us).
// Pre-committed read: ~63-68us => DS/VALU model right; ~78us unchanged =>
// structural floor (clock/launch), probe next with work-doubling.
//
// Math identical to v5 (passed, absmax 0.0156): 3 exact row taps x one 4-col
// 16-bit-packed u64 word; two phase-shifted tile copies so any 3-tap col
// window [j0-1,j0+1] fits one 4-aligned word (4th field = exact bonus tap,
// only helps). Truncation same as v1/v4/v5 (dropped taps >= 1.5 bins,
// weight <= 8.5e-4). Fields .10 fixed point; per-field per-chunk load is 4x
// smaller than v5's (which passed) -> no overflow.

#define BINS   256
#define NPTS   32768
#define BATCH  8
#define TROWS  16                 // rows per tile
#define NTILE  (BINS / TROWS)     // 16 row-tiles
#define CHUNK  4                  // point chunks per batch
#define PPC    (NPTS / CHUNK)     // 8192 points per chunk
#define WORDS  64                 // u64 words per row per phase
#define TILE64 (2 * TROWS * WORDS) // 2048 u64 = 16 KB per partial tile

static constexpr float kInvDelta = 256.0f / 1.5f;                  // 1/DELTA
static constexpr float kUAdd     = 0.25f * (256.0f / 1.5f) - 0.5f; // (x-MIN)/D - 0.5
static constexpr float kPi       = 3.14159265358979323846f;
static constexpr float kFix      = 1024.0f;                        // .10 fixed point
static constexpr float kInvFix   = 1.0f / 1024.0f;

__global__ __launch_bounds__(512) void gh_part(
    const float* __restrict__ x1, const float* __restrict__ x2,
    const float* __restrict__ mask, unsigned long long* __restrict__ ws)
{
    __shared__ unsigned long long tile[TILE64];   // 16 KB
    const int tid = threadIdx.x;
    const int t   = blockIdx.x;            // row-tile
    const int b   = blockIdx.y;            // batch
    const int z   = blockIdx.z;            // point chunk
    const int r0  = t * TROWS;             // first output row owned

#pragma unroll
    for (int i = tid; i < TILE64; i += 512) tile[i] = 0ULL;
    __syncthreads();

    const float4* X1 = (const float4*)(x1   + b * NPTS + z * PPC);
    const float4* X2 = (const float4*)(x2   + b * NPTS + z * PPC);
    const float4* M  = (const float4*)(mask + b * NPTS + z * PPC);

#pragma unroll 2
    for (int it = 0; it < PPC / 2048; ++it) {   // 4 iterations, 4 points each
        const int n4 = it * 512 + tid;
        const float4 a4 = X1[n4];
        const float4 b4 = X2[n4];
        const float4 m4 = M[n4];

        const float pv1[4] = {a4.x, a4.y, a4.z, a4.w};
        const float pv2[4] = {b4.x, b4.y, b4.z, b4.w};
        const float pm[4]  = {m4.x, m4.y, m4.z, m4.w};

#pragma unroll
        for (int k = 0; k < 4; ++k) {
            const float u1 = fmaf(pv1[k], kInvDelta, kUAdd);
            const float u2 = fmaf(pv2[k], kInvDelta, kUAdd);
            const float fi = rintf(u1);
            const int   i0 = (int)fi;
            const float t1 = u1 - fi;             // in [-0.5, 0.5]

            // even window start containing cols [j0-1, j0+1] in 4 cols
            int e = (((int)rintf(u2)) - 1) & ~1;
            e = min(250, max(0, e));              // memory-safety (no-op in-spec)
            const int  ph   = (e >> 1) & 1;       // phase: which tile copy
            const int  word = e >> 2;             // same formula both phases
            const float t2  = u2 - (float)e;      // offset of u2 from col e

            // 3 exact row weights
            float w1a[3];
#pragma unroll
            for (int a = 0; a < 3; ++a) {
                const float d = t1 - (float)(a - 1);
                w1a[a] = __expf(-kPi * d * d);
            }
            // 4 exact col-field weights (mask + fixed scale folded in)
            float W2[4];
#pragma unroll
            for (int c = 0; c < 4; ++c) {
                const float d = t2 - (float)c;
                W2[c] = __expf(-kPi * d * d) * (pm[k] * kFix);
            }

            const int rbase = i0 - 1 - r0;        // tile-relative row of tap a=0
            const int pbase = ph * (TROWS * WORDS) + word;
#pragma unroll
            for (int a = 0; a < 3; ++a) {
                const int r = rbase + a;
                if ((unsigned)r < TROWS) {        // row owned by this block?
                    const float wa = w1a[a];
                    const unsigned f0 = (unsigned)fmaf(wa, W2[0], 0.5f);
                    const unsigned f1 = (unsigned)fmaf(wa, W2[1], 0.5f);
                    const unsigned f2 = (unsigned)fmaf(wa, W2[2], 0.5f);
                    const unsigned f3 = (unsigned)fmaf(wa, W2[3], 0.5f);
                    const unsigned long long w =
                        (unsigned long long)(f0 | (f1 << 16)) |
                        ((unsigned long long)(f2 | (f3 << 16)) << 32);
                    atomicAdd(&tile[pbase + r * WORDS], w);   // ds_add_u64
                }
            }
        }
    }
    __syncthreads();

    // store full partial tile (zeros included -> ws poison fully overwritten)
    unsigned long long* W = ws + (size_t)((b * NTILE + t) * CHUNK + z) * TILE64;
#pragma unroll
    for (int i = tid; i < TILE64; i += 512) W[i] = tile[i];
}

// out[b,r,c] = sum_z sum_ph unpack(ws[b][r/16][z][ph][r%16][...])
__global__ __launch_bounds__(1024) void gh_reduce(
    const unsigned long long* __restrict__ ws, float* __restrict__ out)
{
    const int g     = blockIdx.x * 1024 + threadIdx.x;  // float2 id, 262144 total
    const int cell0 = g * 2;
    const int b     = cell0 >> 16;     // / (256*256)
    const int rem   = cell0 & 65535;
    const int r     = rem >> 8;
    const int c0    = rem & 255;       // even
    const int t     = r >> 4;          // row-tile
    const int rr    = r & 15;

    const unsigned long long* W = ws + (size_t)((b * NTILE + t) * CHUNK) * TILE64;
    unsigned a0 = 0, a1 = 0;
#pragma unroll
    for (int z = 0; z < CHUNK; ++z) {
        const unsigned long long* Z = W + z * TILE64;
        const unsigned long long we = Z[rr * WORDS + (c0 >> 2)];
        a0 += (unsigned)(we >> (16 * (c0 & 3)))       & 0xFFFFu;
        a1 += (unsigned)(we >> (16 * ((c0 + 1) & 3))) & 0xFFFFu;   // same word (c0 even)
        if (c0 >= 2) {
            const unsigned long long wo =
                Z[TROWS * WORDS + rr * WORDS + ((c0 - 2) >> 2)];
            a0 += (unsigned)(wo >> (16 * ((c0 - 2) & 3))) & 0xFFFFu;
            a1 += (unsigned)(wo >> (16 * ((c0 - 1) & 3))) & 0xFFFFu; // same word
        }
    }
    float2 f;
    f.x = (float)a0 * kInvFix;
    f.y = (float)a1 * kInvFix;
    *(float2*)(out + (size_t)cell0) = f;
}

extern "C" void kernel_launch(void* const* d_in, const int* in_sizes, int n_in,
                              void* d_out, int out_size, void* d_ws, size_t ws_size,
                              hipStream_t stream) {
    const float* x1   = (const float*)d_in[0];
    const float* x2   = (const float*)d_in[1];
    const float* mask = (const float*)d_in[2];
    float*       out  = (float*)d_out;
    unsigned long long* ws = (unsigned long long*)d_ws;

    gh_part<<<dim3(NTILE, BATCH, CHUNK), 512, 0, stream>>>(x1, x2, mask, ws);
    gh_reduce<<<dim3(BATCH * BINS * BINS / 2048), 1024, 0, stream>>>(ws, out);
}